// Round 16
// baseline (8195.297 us; speedup 1.0000x reference)
//
#include <hip/hip_runtime.h>

// LSTM scan, persistent, per-element-poison sync + split-bf16 MFMA,
// all-gates-in-lane epilogue. T=512, B=64, D=256, H=512, K=768.
// R16: NU=64 / 1024-thread blocks -> 8 groups x 8 blocks (64 total, 1/CU,
// 16 waves/CU). Producers-per-group 16->8: halves skew tail + poll traffic
// again (R15's -8% lever, final notch). Latency-bound: idle CUs are free.
// Proven sync (R10/R14/R15): h elements self-flagging f32 dwords (poison
// 0x7f7f7f7f, each written once/run) through out; producers fire-and-forget
// sc0 sc1 dword stores; consumers speculatively load + per-thread retry.
// Lessons: LLC-only cross-CU visibility (R6/R7); only plain DWORD sc0 sc1
// stores proven visible (R11-13); explicit vmcnt + sched_barrier after asm
// loads (R8); "=&v" early-clobber; bounded polls.

#define TSTEPS 512
#define BATCH 64
#define DIN 256
#define HID 512
#define KTOT 768
#define BHID (BATCH * HID)   // 32768
#define NB 8                 // batches per group
#define NU 64                // units per block
#define VROW 1064            // shorts/row: [h 512 | xhi 256 | xlo 256 | pad 40]
#define POISON 0x7f7f7f7fu

typedef __attribute__((ext_vector_type(8))) short bf16x8;
typedef __attribute__((ext_vector_type(4))) short bf16x4;
typedef __attribute__((ext_vector_type(4))) float f32x4;

__device__ __forceinline__ float4 llc_load4(const float* p) {
    float4 r; asm volatile("global_load_dwordx4 %0, %1, off sc0 sc1" : "=&v"(r) : "v"(p)); return r;
}
__device__ __forceinline__ void llc_store1(float* p, float v) {
    asm volatile("global_store_dword %0, %1, off sc0 sc1" :: "v"(p), "v"(v) : "memory");
}
__device__ __forceinline__ unsigned short f2bf(float f) {   // RNE float->bf16
    unsigned u = __float_as_uint(f);
    return (unsigned short)((u + 0x7fffu + ((u >> 16) & 1u)) >> 16);
}

__global__ __launch_bounds__(1024, 1)
void lstm_persistent(const float* __restrict__ seqs,
                     const float* __restrict__ h0,
                     const float* __restrict__ c0,
                     const float* __restrict__ Wi, const float* __restrict__ bi,
                     const float* __restrict__ Wf, const float* __restrict__ bff,
                     const float* __restrict__ Wg, const float* __restrict__ bg,
                     const float* __restrict__ Wo, const float* __restrict__ bo,
                     float* __restrict__ out)   // [T+2][B][H]: h0, h1..hT, cT
{
    __shared__ __align__(16) short vv[NB * VROW];   // 17024 B

    const int tid  = threadIdx.x;
    const int bid  = blockIdx.x;
    const int g    = bid >> 3;         // group 0..7: batches [8g, 8g+8)
    const int rblk = bid & 7;          // 0..7: units [64r, 64r+64)
    const int b0 = g * NB;
    const int u0 = rblk * NU;

    const int wv  = tid >> 6;          // wave 0..15: owns units u0+4wv .. +3
    const int l   = tid & 63;
    const int n16 = l & 15;            // A row idx / D col (batch)
    const int khi = (l >> 4) & 3;      // k-subgroup / D row group (unit)
    const int bbr = l & 7;             // B-frag batch row (8-15 broadcast-dup)

    // ---- weights: lane n16 loads row (gate = n16&3, u_local = n16>>2) ----
    const int gsel = n16 & 3;
    const float* Wsel = (gsel == 0) ? Wi : (gsel == 1) ? Wf : (gsel == 2) ? Wg : Wo;
    const float* wrow = Wsel + (size_t)(u0 + 4 * wv + (n16 >> 2)) * KTOT;
    bf16x8 whi[24], wlo[24];
#pragma unroll
    for (int kt = 0; kt < 24; ++kt) {
        const int k0 = kt * 32 + khi * 8;
        const float4 a = *reinterpret_cast<const float4*>(wrow + k0);
        const float4 b = *reinterpret_cast<const float4*>(wrow + k0 + 4);
        const float vals[8] = {a.x, a.y, a.z, a.w, b.x, b.y, b.z, b.w};
        bf16x8 h8, l8;
#pragma unroll
        for (int i = 0; i < 8; ++i) {
            const unsigned short hv = f2bf(vals[i]);
            h8[i] = (short)hv;
            l8[i] = (short)f2bf(vals[i] - __uint_as_float((unsigned)hv << 16));
        }
        whi[kt] = h8; wlo[kt] = l8;
    }

    // ---- per-lane epilogue state: biases + c (unit_d, batch_d) ----
    const int unit_d  = u0 + 4 * wv + khi;
    const int batch_d = b0 + (n16 & 7);          // lanes 8-15 unused in E
    const float bI = bi[unit_d],  bF = bff[unit_d];
    const float bG = bg[unit_d],  bO = bo[unit_d];
    float creg = c0[(size_t)batch_d * HID + unit_d];

    if (tid < 512) {   // allhidden[0] = h0 slice (plain; never polled)
        const int uu = tid & 63, bb = tid >> 6;
        out[(size_t)(b0 + bb) * HID + u0 + uu] = h0[(size_t)(b0 + bb) * HID + u0 + uu];
    }

    // ---- pre-loop staging: h0 (bf16-hi) and x0 (hi+lo) -> LDS ----
    {
        const int b = tid >> 7, k0 = (tid & 127) * 4;    // 4 h-floats/thread
        const float4 t4 = *reinterpret_cast<const float4*>(
            h0 + (size_t)(b0 + b) * HID + k0);
        bf16x4 a4;
        a4[0] = (short)f2bf(t4.x); a4[1] = (short)f2bf(t4.y);
        a4[2] = (short)f2bf(t4.z); a4[3] = (short)f2bf(t4.w);
        *reinterpret_cast<bf16x4*>(&vv[b * VROW + k0]) = a4;
    }
    if (tid < 512) {
        const int b = tid >> 6, kx = (tid & 63) * 4;     // 4 x-floats/thread
        const float4 t4 = *reinterpret_cast<const float4*>(
            seqs + (size_t)(b0 + b) * DIN + kx);
        const float xv[4] = {t4.x, t4.y, t4.z, t4.w};
        bf16x4 a4, la4;
#pragma unroll
        for (int i = 0; i < 4; ++i) {
            const unsigned short h1 = f2bf(xv[i]);
            a4[i]  = (short)h1;
            la4[i] = (short)f2bf(xv[i] - __uint_as_float((unsigned)h1 << 16));
        }
        *reinterpret_cast<bf16x4*>(&vv[b * VROW + 512 + kx]) = a4;
        *reinterpret_cast<bf16x4*>(&vv[b * VROW + 768 + kx]) = la4;
    }
    __syncthreads();

    const short* vrow = &vv[bbr * VROW + khi * 8];

    for (int t = 0; t < TSTEPS; ++t) {
        // ---- C0: issue speculative h_t load BEFORE the x-MFMA phase ----
        const int cb = tid >> 7, ck = (tid & 127) * 4;
        const float* hpf = out + (size_t)t * BHID + (size_t)(b0 + cb) * HID + ck;
        float4 hb0;
        if (t > 0) hb0 = llc_load4(hpf);

        // ---- A: x-part MFMA (uses x_t; overlaps other blocks' h_t tails) ----
        f32x4 aA = {0.f,0.f,0.f,0.f}, aB = {0.f,0.f,0.f,0.f}, aC = {0.f,0.f,0.f,0.f};
#pragma unroll
        for (int kt = 0; kt < 8; ++kt) {
            const bf16x8 bh = *reinterpret_cast<const bf16x8*>(vrow + 512 + kt * 32);
            const bf16x8 bl = *reinterpret_cast<const bf16x8*>(vrow + 768 + kt * 32);
            aA = __builtin_amdgcn_mfma_f32_16x16x32_bf16(whi[16 + kt], bh, aA, 0, 0, 0);
            aB = __builtin_amdgcn_mfma_f32_16x16x32_bf16(wlo[16 + kt], bh, aB, 0, 0, 0);
            aC = __builtin_amdgcn_mfma_f32_16x16x32_bf16(whi[16 + kt], bl, aC, 0, 0, 0);
        }

        // ---- B: issue x_{t+1} loads (complete under C/D) ----
        float4 xr0;
        const bool do_x = (t + 1 < TSTEPS) && (tid < 512);
        if (do_x) {
            xr0 = *reinterpret_cast<const float4*>(
                seqs + (size_t)(t + 1) * BATCH * DIN
                + (size_t)(b0 + (tid >> 6)) * DIN + (tid & 63) * 4);
        }

        // ---- C (t>0): speculative poll — data is its own flag ----
        if (t > 0) {
            unsigned miss = 0;
            for (;;) {
                asm volatile("s_waitcnt vmcnt(0)" ::: "memory");
                __builtin_amdgcn_sched_barrier(0);
                bool ok = true;
                ok &= (__float_as_uint(hb0.x) != POISON);
                ok &= (__float_as_uint(hb0.y) != POISON);
                ok &= (__float_as_uint(hb0.z) != POISON);
                ok &= (__float_as_uint(hb0.w) != POISON);
                if (ok) break;                    // per-thread readiness only
                if (++miss > (1u << 20)) break;   // bounded: never hang
                __builtin_amdgcn_s_sleep(1);
                hb0 = llc_load4(hpf);
            }
            bf16x4 a4;
            a4[0] = (short)f2bf(hb0.x); a4[1] = (short)f2bf(hb0.y);
            a4[2] = (short)f2bf(hb0.z); a4[3] = (short)f2bf(hb0.w);
            *reinterpret_cast<bf16x4*>(&vv[cb * VROW + ck]) = a4;
        }
        __syncthreads();   // h_t staged block-wide

        // ---- D: h-part MFMA (2 chains, h bf16-hi) ----
#pragma unroll
        for (int kt = 0; kt < 16; ++kt) {
            const bf16x8 bh = *reinterpret_cast<const bf16x8*>(vrow + kt * 32);
            aA = __builtin_amdgcn_mfma_f32_16x16x32_bf16(whi[kt], bh, aA, 0, 0, 0);
            aB = __builtin_amdgcn_mfma_f32_16x16x32_bf16(wlo[kt], bh, aB, 0, 0, 0);
        }
        const f32x4 gA = aA + aB + aC;   // gA[r] = gate r of (unit_d, batch_d)

        // ---- E: lane-local elementwise + fire-and-forget dword h store ----
        if (n16 < 8) {
            const float gi = gA[0] + bI;
            const float gf = gA[1] + bF;
            const float gG = gA[2] + bG;
            const float go = gA[3] + bO;
            const float i_ = 1.f / (1.f + __expf(-gi));
            const float f_ = 1.f / (1.f + __expf(-gf));
            const float o_ = 1.f / (1.f + __expf(-go));
            float eg = __expf(-2.f * fabsf(gG));
            float tg = (1.f - eg) / (1.f + eg);
            tg = (gG < 0.f) ? -tg : tg;
            creg = f_ * creg + i_ * tg;
            float ec = __expf(-2.f * fabsf(creg));
            float tc = (1.f - ec) / (1.f + ec);
            tc = (creg < 0.f) ? -tc : tc;
            const float hn = o_ * tc;
            llc_store1(out + (size_t)(t + 1) * BHID + (size_t)batch_d * HID + unit_d, hn);
            if (t == TSTEPS - 1)
                out[(size_t)(TSTEPS + 1) * BHID + (size_t)batch_d * HID + unit_d] = creg;
        }

        // ---- F: x_{t+1} cvt -> LDS ----
        if (do_x) {
            const int b = tid >> 6, kx = (tid & 63) * 4;
            const float xv[4] = {xr0.x, xr0.y, xr0.z, xr0.w};
            bf16x4 a4, la4;
#pragma unroll
            for (int i = 0; i < 4; ++i) {
                const unsigned short h1 = f2bf(xv[i]);
                a4[i]  = (short)h1;
                la4[i] = (short)f2bf(xv[i] - __uint_as_float((unsigned)h1 << 16));
            }
            *reinterpret_cast<bf16x4*>(&vv[b * VROW + 512 + kx]) = a4;
            *reinterpret_cast<bf16x4*>(&vv[b * VROW + 768 + kx]) = la4;
        }
        __syncthreads();   // x_{t+1} staged; h region free for next C
    }
}

extern "C" void kernel_launch(void* const* d_in, const int* in_sizes, int n_in,
                              void* d_out, int out_size, void* d_ws, size_t ws_size,
                              hipStream_t stream) {
    const float* seqs = (const float*)d_in[0];
    const float* h0   = (const float*)d_in[1];
    const float* c0   = (const float*)d_in[2];
    const float* Wi   = (const float*)d_in[3];
    const float* bi   = (const float*)d_in[4];
    const float* Wf   = (const float*)d_in[5];
    const float* bf   = (const float*)d_in[6];
    const float* Wg   = (const float*)d_in[7];
    const float* bg   = (const float*)d_in[8];
    const float* Wo   = (const float*)d_in[9];
    const float* bo   = (const float*)d_in[10];
    float* out = (float*)d_out;

    // Poison h[1..T] every launch: each element is written exactly once per
    // run, so the data itself is the readiness flag (graph-replay safe).
    hipMemsetAsync((char*)out + (size_t)BHID * 4, 0x7f,
                   (size_t)TSTEPS * BHID * 4, stream);

    hipLaunchKernelGGL(lstm_persistent, dim3(64), dim3(1024), 0, stream,
                       seqs, h0, c0, Wi, bi, Wf, bf, Wg, bg, Wo, bo, out);
}

// Round 17
// 2090.852 us; speedup vs baseline: 3.9196x; 3.9196x over previous
//
#include <hip/hip_runtime.h>

// LSTM scan, persistent, per-element-poison sync + split-bf16 MFMA,
// all-gates-in-lane epilogue, CHUNKED h-consumption pipeline.
// T=512, B=64, D=256, H=512, K=768.
// R17 = R15 (8 groups x 16 blocks, 512 thr, NU=32 — best: 1251us) with the
// h poll+MFMA split into 4 chunks of 128 units (4 producer blocks each):
//   for c in 0..3: {wave-pair c polls+stages chunk c} barrier {all: MFMA 4 tiles}
// Late chunks' detect overlaps earlier chunks' MFMA -> absorbs producer skew.
// Chunk loops fully unrolled (whi[kt] must stay compile-time indexed: R16's
// 1024-thr VGPR cliff proved runtime indexing/spill costs 6x). Poll branch is
// wave-uniform (wave-pair <-> chunk).
// Proven sync (R10/R14/R15): h as self-flagging f32 dwords (poison 0x7f7f7f7f,
// each written once/run) via out; fire-and-forget sc0 sc1 dword stores;
// speculative loads + per-thread retry. Lessons: LLC-only visibility (R6/R7);
// only plain DWORD sc0 sc1 stores visible (R11-13); vmcnt+sched_barrier after
// asm loads (R8); "=&v"; bounded polls; <=512 thr/block (R16 register cliff).

#define TSTEPS 512
#define BATCH 64
#define DIN 256
#define HID 512
#define KTOT 768
#define BHID (BATCH * HID)   // 32768
#define NB 8                 // batches per group
#define NU 32                // units per block
#define VROW 1064            // shorts/row: [h 512 | xhi 256 | xlo 256 | pad 40]
#define POISON 0x7f7f7f7fu

typedef __attribute__((ext_vector_type(8))) short bf16x8;
typedef __attribute__((ext_vector_type(4))) float f32x4;

__device__ __forceinline__ float4 llc_load4(const float* p) {
    float4 r; asm volatile("global_load_dwordx4 %0, %1, off sc0 sc1" : "=&v"(r) : "v"(p)); return r;
}
__device__ __forceinline__ void llc_store1(float* p, float v) {
    asm volatile("global_store_dword %0, %1, off sc0 sc1" :: "v"(p), "v"(v) : "memory");
}
__device__ __forceinline__ unsigned short f2bf(float f) {   // RNE float->bf16
    unsigned u = __float_as_uint(f);
    return (unsigned short)((u + 0x7fffu + ((u >> 16) & 1u)) >> 16);
}

__global__ __launch_bounds__(512, 1)
void lstm_persistent(const float* __restrict__ seqs,
                     const float* __restrict__ h0,
                     const float* __restrict__ c0,
                     const float* __restrict__ Wi, const float* __restrict__ bi,
                     const float* __restrict__ Wf, const float* __restrict__ bff,
                     const float* __restrict__ Wg, const float* __restrict__ bg,
                     const float* __restrict__ Wo, const float* __restrict__ bo,
                     float* __restrict__ out)   // [T+2][B][H]: h0, h1..hT, cT
{
    __shared__ __align__(16) short vv[NB * VROW];   // 17024 B

    const int tid  = threadIdx.x;
    const int bid  = blockIdx.x;
    const int g    = bid >> 4;         // group 0..7: batches [8g, 8g+8)
    const int rblk = bid & 15;         // 0..15: units [32r, 32r+32)
    const int b0 = g * NB;
    const int u0 = rblk * NU;

    const int wv  = tid >> 6;          // wave 0..7: owns units u0+4wv .. +3
    const int l   = tid & 63;
    const int n16 = l & 15;            // A row idx / D col (batch)
    const int khi = (l >> 4) & 3;      // k-subgroup / D row group (unit)
    const int bbr = l & 7;             // B-frag batch row (8-15 broadcast-dup)

    // ---- weights: lane n16 loads row (gate = n16&3, u_local = n16>>2) ----
    const int gsel = n16 & 3;
    const float* Wsel = (gsel == 0) ? Wi : (gsel == 1) ? Wf : (gsel == 2) ? Wg : Wo;
    const float* wrow = Wsel + (size_t)(u0 + 4 * wv + (n16 >> 2)) * KTOT;
    bf16x8 whi[24], wlo[24];
#pragma unroll
    for (int kt = 0; kt < 24; ++kt) {
        const int k0 = kt * 32 + khi * 8;
        const float4 a = *reinterpret_cast<const float4*>(wrow + k0);
        const float4 b = *reinterpret_cast<const float4*>(wrow + k0 + 4);
        const float vals[8] = {a.x, a.y, a.z, a.w, b.x, b.y, b.z, b.w};
        bf16x8 h8, l8;
#pragma unroll
        for (int i = 0; i < 8; ++i) {
            const unsigned short hv = f2bf(vals[i]);
            h8[i] = (short)hv;
            l8[i] = (short)f2bf(vals[i] - __uint_as_float((unsigned)hv << 16));
        }
        whi[kt] = h8; wlo[kt] = l8;
    }

    // ---- per-lane epilogue state: biases + c (unit_d, batch_d) ----
    const int unit_d  = u0 + 4 * wv + khi;
    const int batch_d = b0 + (n16 & 7);          // lanes 8-15 unused in E
    const float bI = bi[unit_d],  bF = bff[unit_d];
    const float bG = bg[unit_d],  bO = bo[unit_d];
    float creg = c0[(size_t)batch_d * HID + unit_d];

    if (tid < 256) {   // allhidden[0] = h0 slice (plain; never polled)
        const int uu = tid & 31, bb = tid >> 5;
        out[(size_t)(b0 + bb) * HID + u0 + uu] = h0[(size_t)(b0 + bb) * HID + u0 + uu];
    }

    // ---- consumer mapping: wave-pair (wv>>1) owns chunk c of 128 units ----
    const int cwv = wv >> 1;                        // my chunk 0..3
    const int cb  = l >> 3;                         // batch 0..7
    const int uk  = cwv * 128 + (wv & 1) * 64 + (l & 7) * 8;   // 8 units

    // ---- pre-loop staging: h0 (bf16-hi) and x0 (hi+lo) -> LDS ----
    {
        const int b = tid >> 6, k0 = (tid & 63) * 8;
        const float* hp = h0 + (size_t)(b0 + b) * HID + k0;
        const float4 t0 = reinterpret_cast<const float4*>(hp)[0];
        const float4 t1 = reinterpret_cast<const float4*>(hp)[1];
        const float hv[8] = {t0.x, t0.y, t0.z, t0.w, t1.x, t1.y, t1.z, t1.w};
        bf16x8 a8;
#pragma unroll
        for (int i = 0; i < 8; ++i) a8[i] = (short)f2bf(hv[i]);
        *reinterpret_cast<bf16x8*>(&vv[b * VROW + k0]) = a8;
    }
    if (tid < 256) {
        const int b = tid >> 5, kx = (tid & 31) * 8;
        const float* xp = seqs + (size_t)(b0 + b) * DIN + kx;
        const float4 t0 = reinterpret_cast<const float4*>(xp)[0];
        const float4 t1 = reinterpret_cast<const float4*>(xp)[1];
        const float xv[8] = {t0.x, t0.y, t0.z, t0.w, t1.x, t1.y, t1.z, t1.w};
        bf16x8 a8, la8;
#pragma unroll
        for (int i = 0; i < 8; ++i) {
            const unsigned short h1 = f2bf(xv[i]);
            a8[i]  = (short)h1;
            la8[i] = (short)f2bf(xv[i] - __uint_as_float((unsigned)h1 << 16));
        }
        *reinterpret_cast<bf16x8*>(&vv[b * VROW + 512 + kx]) = a8;
        *reinterpret_cast<bf16x8*>(&vv[b * VROW + 768 + kx]) = la8;
    }
    __syncthreads();

    const short* vrow = &vv[bbr * VROW + khi * 8];

    for (int t = 0; t < TSTEPS; ++t) {
        // ---- C0: issue speculative h_t loads BEFORE the x-MFMA phase ----
        const float* hpf = out + (size_t)t * BHID + (size_t)(b0 + cb) * HID + uk;
        float4 hb0, hb1;
        if (t > 0) { hb0 = llc_load4(hpf); hb1 = llc_load4(hpf + 4); }

        // ---- A: x-part MFMA (uses x_t; overlaps other blocks' h_t tails) ----
        f32x4 aA = {0.f,0.f,0.f,0.f}, aB = {0.f,0.f,0.f,0.f}, aC = {0.f,0.f,0.f,0.f};
#pragma unroll
        for (int kt = 0; kt < 8; ++kt) {
            const bf16x8 bh = *reinterpret_cast<const bf16x8*>(vrow + 512 + kt * 32);
            const bf16x8 bl = *reinterpret_cast<const bf16x8*>(vrow + 768 + kt * 32);
            aA = __builtin_amdgcn_mfma_f32_16x16x32_bf16(whi[16 + kt], bh, aA, 0, 0, 0);
            aB = __builtin_amdgcn_mfma_f32_16x16x32_bf16(wlo[16 + kt], bh, aB, 0, 0, 0);
            aC = __builtin_amdgcn_mfma_f32_16x16x32_bf16(whi[16 + kt], bl, aC, 0, 0, 0);
        }

        // ---- B: issue x_{t+1} loads (complete under the chunk loop) ----
        float4 xr0, xr1;
        const bool do_x = (t + 1 < TSTEPS) && (tid < 256);
        if (do_x) {
            const float* xp = seqs + (size_t)(t + 1) * BATCH * DIN
                            + (size_t)(b0 + (tid >> 5)) * DIN + (tid & 31) * 8;
            xr0 = reinterpret_cast<const float4*>(xp)[0];
            xr1 = reinterpret_cast<const float4*>(xp)[1];
        }

        // ---- chunked h pipeline: poll chunk c -> barrier -> MFMA 4 tiles ----
#pragma unroll
        for (int c = 0; c < 4; ++c) {
            if (t > 0 && cwv == c) {      // wave-uniform branch
                unsigned miss = 0;
                for (;;) {
                    asm volatile("s_waitcnt vmcnt(0)" ::: "memory");
                    __builtin_amdgcn_sched_barrier(0);
                    bool ok = true;
                    ok &= (__float_as_uint(hb0.x) != POISON);
                    ok &= (__float_as_uint(hb0.y) != POISON);
                    ok &= (__float_as_uint(hb0.z) != POISON);
                    ok &= (__float_as_uint(hb0.w) != POISON);
                    ok &= (__float_as_uint(hb1.x) != POISON);
                    ok &= (__float_as_uint(hb1.y) != POISON);
                    ok &= (__float_as_uint(hb1.z) != POISON);
                    ok &= (__float_as_uint(hb1.w) != POISON);
                    if (ok) break;                    // per-thread readiness
                    if (++miss > (1u << 20)) break;   // bounded: never hang
                    __builtin_amdgcn_s_sleep(1);
                    hb0 = llc_load4(hpf); hb1 = llc_load4(hpf + 4);
                }
                bf16x8 a8;
                a8[0] = (short)f2bf(hb0.x); a8[1] = (short)f2bf(hb0.y);
                a8[2] = (short)f2bf(hb0.z); a8[3] = (short)f2bf(hb0.w);
                a8[4] = (short)f2bf(hb1.x); a8[5] = (short)f2bf(hb1.y);
                a8[6] = (short)f2bf(hb1.z); a8[7] = (short)f2bf(hb1.w);
                *reinterpret_cast<bf16x8*>(&vv[cb * VROW + uk]) = a8;
            }
            __syncthreads();   // chunk c staged block-wide
#pragma unroll
            for (int j = 0; j < 4; ++j) {
                const int kt = c * 4 + j;   // compile-time (both loops unrolled)
                const bf16x8 bh = *reinterpret_cast<const bf16x8*>(vrow + kt * 32);
                aA = __builtin_amdgcn_mfma_f32_16x16x32_bf16(whi[kt], bh, aA, 0, 0, 0);
                aB = __builtin_amdgcn_mfma_f32_16x16x32_bf16(wlo[kt], bh, aB, 0, 0, 0);
            }
        }
        const f32x4 gA = aA + aB + aC;   // gA[r] = gate r of (unit_d, batch_d)

        // ---- E: lane-local elementwise + fire-and-forget dword h store ----
        if (n16 < 8) {
            const float gi = gA[0] + bI;
            const float gf = gA[1] + bF;
            const float gG = gA[2] + bG;
            const float go = gA[3] + bO;
            const float i_ = 1.f / (1.f + __expf(-gi));
            const float f_ = 1.f / (1.f + __expf(-gf));
            const float o_ = 1.f / (1.f + __expf(-go));
            float eg = __expf(-2.f * fabsf(gG));
            float tg = (1.f - eg) / (1.f + eg);
            tg = (gG < 0.f) ? -tg : tg;
            creg = f_ * creg + i_ * tg;
            float ec = __expf(-2.f * fabsf(creg));
            float tc = (1.f - ec) / (1.f + ec);
            tc = (creg < 0.f) ? -tc : tc;
            const float hn = o_ * tc;
            llc_store1(out + (size_t)(t + 1) * BHID + (size_t)batch_d * HID + unit_d, hn);
            if (t == TSTEPS - 1)
                out[(size_t)(TSTEPS + 1) * BHID + (size_t)batch_d * HID + unit_d] = creg;
        }

        // ---- F: x_{t+1} cvt -> LDS ----
        if (do_x) {
            const int b = tid >> 5, kx = (tid & 31) * 8;
            const float xv[8] = {xr0.x, xr0.y, xr0.z, xr0.w, xr1.x, xr1.y, xr1.z, xr1.w};
            bf16x8 a8, la8;
#pragma unroll
            for (int i = 0; i < 8; ++i) {
                const unsigned short h1 = f2bf(xv[i]);
                a8[i]  = (short)h1;
                la8[i] = (short)f2bf(xv[i] - __uint_as_float((unsigned)h1 << 16));
            }
            *reinterpret_cast<bf16x8*>(&vv[b * VROW + 512 + kx]) = a8;
            *reinterpret_cast<bf16x8*>(&vv[b * VROW + 768 + kx]) = la8;
        }
        __syncthreads();   // x_{t+1} staged; h region free for next step
    }
}

extern "C" void kernel_launch(void* const* d_in, const int* in_sizes, int n_in,
                              void* d_out, int out_size, void* d_ws, size_t ws_size,
                              hipStream_t stream) {
    const float* seqs = (const float*)d_in[0];
    const float* h0   = (const float*)d_in[1];
    const float* c0   = (const float*)d_in[2];
    const float* Wi   = (const float*)d_in[3];
    const float* bi   = (const float*)d_in[4];
    const float* Wf   = (const float*)d_in[5];
    const float* bf   = (const float*)d_in[6];
    const float* Wg   = (const float*)d_in[7];
    const float* bg   = (const float*)d_in[8];
    const float* Wo   = (const float*)d_in[9];
    const float* bo   = (const float*)d_in[10];
    float* out = (float*)d_out;

    // Poison h[1..T] every launch: each element is written exactly once per
    // run, so the data itself is the readiness flag (graph-replay safe).
    hipMemsetAsync((char*)out + (size_t)BHID * 4, 0x7f,
                   (size_t)TSTEPS * BHID * 4, stream);

    hipLaunchKernelGGL(lstm_persistent, dim3(128), dim3(512), 0, stream,
                       seqs, h0, c0, Wi, bi, Wf, bf, Wg, bg, Wo, bo, out);
}

// Round 18
// 1999.735 us; speedup vs baseline: 4.0982x; 1.0456x over previous
//
#include <hip/hip_runtime.h>

// LSTM scan, persistent, per-element-poison sync + split-bf16 MFMA,
// all-gates-in-lane epilogue, SINGLE-BARRIER double-buffered LDS.
// T=512, B=64, D=256, H=512, K=768.
// R18 = R15 (8 groups x 16 blocks, 512 thr, NU=32 — best: 1251us) with the
// end-of-loop barrier removed: h and x LDS double-buffered (parity t&1),
// x staged TWO steps ahead (B(t) loads x_{t+2}, F(t) writes parity t&1).
// Safety: A(t+1) reads x written by F(t-1) -- separated by MID(t); D(t) h
// reads vs C(t+1) h writes are opposite parity; 2-iter skew blocked by
// MID(t+1). Gain: one barrier/step removed; fast waves' poll overlaps slow
// waves' epilogue (R17's chunking serialized this; dbuf overlaps it).
// Proven sync (R10/R14/R15): h as self-flagging f32 dwords (poison
// 0x7f7f7f7f, written once/run) via out; fire-and-forget sc0 sc1 dword
// stores; speculative loads + per-thread retry. Lessons: LLC-only visibility
// (R6/R7); only DWORD sc0 sc1 stores visible (R11-13); vmcnt+sched_barrier
// after asm loads (R8); "=&v"; bounded polls; <=512 thr (R16 VGPR cliff).

#define TSTEPS 512
#define BATCH 64
#define DIN 256
#define HID 512
#define KTOT 768
#define BHID (BATCH * HID)   // 32768
#define NB 8                 // batches per group
#define NU 32                // units per block
#define POISON 0x7f7f7f7fu
#define HROW 520             // shorts per h row (260 dwords = 4 mod 32)
#define XROW 264             // shorts per x row (132 dwords = 4 mod 32)

typedef __attribute__((ext_vector_type(8))) short bf16x8;
typedef __attribute__((ext_vector_type(4))) float f32x4;

__device__ __forceinline__ float4 llc_load4(const float* p) {
    float4 r; asm volatile("global_load_dwordx4 %0, %1, off sc0 sc1" : "=&v"(r) : "v"(p)); return r;
}
__device__ __forceinline__ void llc_store1(float* p, float v) {
    asm volatile("global_store_dword %0, %1, off sc0 sc1" :: "v"(p), "v"(v) : "memory");
}
__device__ __forceinline__ unsigned short f2bf(float f) {   // RNE float->bf16
    unsigned u = __float_as_uint(f);
    return (unsigned short)((u + 0x7fffu + ((u >> 16) & 1u)) >> 16);
}

__global__ __launch_bounds__(512, 1)
void lstm_persistent(const float* __restrict__ seqs,
                     const float* __restrict__ h0,
                     const float* __restrict__ c0,
                     const float* __restrict__ Wi, const float* __restrict__ bi,
                     const float* __restrict__ Wf, const float* __restrict__ bff,
                     const float* __restrict__ Wg, const float* __restrict__ bg,
                     const float* __restrict__ Wo, const float* __restrict__ bo,
                     float* __restrict__ out)   // [T+2][B][H]: h0, h1..hT, cT
{
    __shared__ __align__(16) short hb_s[2][NB][HROW];   // 16640 B
    __shared__ __align__(16) short xh_s[2][NB][XROW];   //  8448 B
    __shared__ __align__(16) short xl_s[2][NB][XROW];   //  8448 B

    const int tid  = threadIdx.x;
    const int bid  = blockIdx.x;
    const int g    = bid >> 4;         // group 0..7: batches [8g, 8g+8)
    const int rblk = bid & 15;         // 0..15: units [32r, 32r+32)
    const int b0 = g * NB;
    const int u0 = rblk * NU;

    const int wv  = tid >> 6;          // wave 0..7: owns units u0+4wv .. +3
    const int l   = tid & 63;
    const int n16 = l & 15;            // A row idx / D col (batch)
    const int khi = (l >> 4) & 3;      // k-subgroup / D row group (unit)
    const int bbr = l & 7;             // B-frag batch row (8-15 broadcast-dup)

    // ---- weights: lane n16 loads row (gate = n16&3, u_local = n16>>2) ----
    const int gsel = n16 & 3;
    const float* Wsel = (gsel == 0) ? Wi : (gsel == 1) ? Wf : (gsel == 2) ? Wg : Wo;
    const float* wrow = Wsel + (size_t)(u0 + 4 * wv + (n16 >> 2)) * KTOT;
    bf16x8 whi[24], wlo[24];
#pragma unroll
    for (int kt = 0; kt < 24; ++kt) {
        const int k0 = kt * 32 + khi * 8;
        const float4 a = *reinterpret_cast<const float4*>(wrow + k0);
        const float4 b = *reinterpret_cast<const float4*>(wrow + k0 + 4);
        const float vals[8] = {a.x, a.y, a.z, a.w, b.x, b.y, b.z, b.w};
        bf16x8 h8, l8;
#pragma unroll
        for (int i = 0; i < 8; ++i) {
            const unsigned short hv = f2bf(vals[i]);
            h8[i] = (short)hv;
            l8[i] = (short)f2bf(vals[i] - __uint_as_float((unsigned)hv << 16));
        }
        whi[kt] = h8; wlo[kt] = l8;
    }

    // ---- per-lane epilogue state: biases + c (unit_d, batch_d) ----
    const int unit_d  = u0 + 4 * wv + khi;
    const int batch_d = b0 + (n16 & 7);          // lanes 8-15 unused in E
    const float bI = bi[unit_d],  bF = bff[unit_d];
    const float bG = bg[unit_d],  bO = bo[unit_d];
    float creg = c0[(size_t)batch_d * HID + unit_d];

    if (tid < 256) {   // allhidden[0] = h0 slice (plain; never polled)
        const int uu = tid & 31, bb = tid >> 5;
        out[(size_t)(b0 + bb) * HID + u0 + uu] = h0[(size_t)(b0 + bb) * HID + u0 + uu];
    }

    // ---- pre-loop staging: h0 -> hb[0]; x0 -> x[0]; x1 -> x[1] ----
    {
        const int b = tid >> 6, k0 = (tid & 63) * 8;
        const float* hp = h0 + (size_t)(b0 + b) * HID + k0;
        const float4 t0 = reinterpret_cast<const float4*>(hp)[0];
        const float4 t1 = reinterpret_cast<const float4*>(hp)[1];
        const float hv[8] = {t0.x, t0.y, t0.z, t0.w, t1.x, t1.y, t1.z, t1.w};
        bf16x8 a8;
#pragma unroll
        for (int i = 0; i < 8; ++i) a8[i] = (short)f2bf(hv[i]);
        *reinterpret_cast<bf16x8*>(&hb_s[0][b][k0]) = a8;
    }
    if (tid < 256) {
        const int b = tid >> 5, kx = (tid & 31) * 8;
#pragma unroll
        for (int s = 0; s < 2; ++s) {    // x0 -> buf0, x1 -> buf1
            const float* xp = seqs + (size_t)s * BATCH * DIN
                            + (size_t)(b0 + b) * DIN + kx;
            const float4 t0 = reinterpret_cast<const float4*>(xp)[0];
            const float4 t1 = reinterpret_cast<const float4*>(xp)[1];
            const float xv[8] = {t0.x, t0.y, t0.z, t0.w, t1.x, t1.y, t1.z, t1.w};
            bf16x8 a8, la8;
#pragma unroll
            for (int i = 0; i < 8; ++i) {
                const unsigned short h1 = f2bf(xv[i]);
                a8[i]  = (short)h1;
                la8[i] = (short)f2bf(xv[i] - __uint_as_float((unsigned)h1 << 16));
            }
            *reinterpret_cast<bf16x8*>(&xh_s[s][b][kx]) = a8;
            *reinterpret_cast<bf16x8*>(&xl_s[s][b][kx]) = la8;
        }
    }
    __syncthreads();

    for (int t = 0; t < TSTEPS; ++t) {
        const int p = t & 1;   // LDS parity for this step's h and x

        // ---- C0: issue speculative h_t loads BEFORE the x-MFMA phase ----
        const int cb = tid >> 6, ck = (tid & 63) * 8;
        const float* hpf = out + (size_t)t * BHID + (size_t)(b0 + cb) * HID + ck;
        float4 hb0, hb1;
        if (t > 0) { hb0 = llc_load4(hpf); hb1 = llc_load4(hpf + 4); }

        // ---- A: x-part MFMA (x_t from parity p; h-independent) ----
        f32x4 aA = {0.f,0.f,0.f,0.f}, aB = {0.f,0.f,0.f,0.f}, aC = {0.f,0.f,0.f,0.f};
        const short* xrh = &xh_s[p][bbr][khi * 8];
        const short* xrl = &xl_s[p][bbr][khi * 8];
#pragma unroll
        for (int kt = 0; kt < 8; ++kt) {
            const bf16x8 bh = *reinterpret_cast<const bf16x8*>(xrh + kt * 32);
            const bf16x8 bl = *reinterpret_cast<const bf16x8*>(xrl + kt * 32);
            aA = __builtin_amdgcn_mfma_f32_16x16x32_bf16(whi[16 + kt], bh, aA, 0, 0, 0);
            aB = __builtin_amdgcn_mfma_f32_16x16x32_bf16(wlo[16 + kt], bh, aB, 0, 0, 0);
            aC = __builtin_amdgcn_mfma_f32_16x16x32_bf16(whi[16 + kt], bl, aC, 0, 0, 0);
        }

        // ---- B: issue x_{t+2} loads (staged into parity p at F) ----
        float4 xr0, xr1;
        const bool do_x = (t + 2 < TSTEPS) && (tid < 256);
        if (do_x) {
            const float* xp = seqs + (size_t)(t + 2) * BATCH * DIN
                            + (size_t)(b0 + (tid >> 5)) * DIN + (tid & 31) * 8;
            xr0 = reinterpret_cast<const float4*>(xp)[0];
            xr1 = reinterpret_cast<const float4*>(xp)[1];
        }

        // ---- C (t>0): speculative poll — data is its own flag ----
        if (t > 0) {
            unsigned miss = 0;
            for (;;) {
                asm volatile("s_waitcnt vmcnt(0)" ::: "memory");
                __builtin_amdgcn_sched_barrier(0);
                bool ok = true;
                ok &= (__float_as_uint(hb0.x) != POISON);
                ok &= (__float_as_uint(hb0.y) != POISON);
                ok &= (__float_as_uint(hb0.z) != POISON);
                ok &= (__float_as_uint(hb0.w) != POISON);
                ok &= (__float_as_uint(hb1.x) != POISON);
                ok &= (__float_as_uint(hb1.y) != POISON);
                ok &= (__float_as_uint(hb1.z) != POISON);
                ok &= (__float_as_uint(hb1.w) != POISON);
                if (ok) break;                    // per-thread readiness only
                if (++miss > (1u << 20)) break;   // bounded: never hang
                __builtin_amdgcn_s_sleep(1);
                hb0 = llc_load4(hpf); hb1 = llc_load4(hpf + 4);
            }
            const float hv[8] = {hb0.x, hb0.y, hb0.z, hb0.w, hb1.x, hb1.y, hb1.z, hb1.w};
            bf16x8 a8;
#pragma unroll
            for (int i = 0; i < 8; ++i) a8[i] = (short)f2bf(hv[i]);
            *reinterpret_cast<bf16x8*>(&hb_s[p][cb][ck]) = a8;
        }
        __syncthreads();   // MID: h_t (parity p) staged block-wide

        // ---- D: h-part MFMA (2 chains, h bf16-hi, parity p) ----
        const short* hr = &hb_s[p][bbr][khi * 8];
#pragma unroll
        for (int kt = 0; kt < 16; ++kt) {
            const bf16x8 bh = *reinterpret_cast<const bf16x8*>(hr + kt * 32);
            aA = __builtin_amdgcn_mfma_f32_16x16x32_bf16(whi[kt], bh, aA, 0, 0, 0);
            aB = __builtin_amdgcn_mfma_f32_16x16x32_bf16(wlo[kt], bh, aB, 0, 0, 0);
        }
        const f32x4 gA = aA + aB + aC;   // gA[r] = gate r of (unit_d, batch_d)

        // ---- E: lane-local elementwise + fire-and-forget dword h store ----
        if (n16 < 8) {
            const float gi = gA[0] + bI;
            const float gf = gA[1] + bF;
            const float gG = gA[2] + bG;
            const float go = gA[3] + bO;
            const float i_ = 1.f / (1.f + __expf(-gi));
            const float f_ = 1.f / (1.f + __expf(-gf));
            const float o_ = 1.f / (1.f + __expf(-go));
            float eg = __expf(-2.f * fabsf(gG));
            float tg = (1.f - eg) / (1.f + eg);
            tg = (gG < 0.f) ? -tg : tg;
            creg = f_ * creg + i_ * tg;
            float ec = __expf(-2.f * fabsf(creg));
            float tc = (1.f - ec) / (1.f + ec);
            tc = (creg < 0.f) ? -tc : tc;
            const float hn = o_ * tc;
            llc_store1(out + (size_t)(t + 1) * BHID + (size_t)batch_d * HID + unit_d, hn);
            if (t == TSTEPS - 1)
                out[(size_t)(TSTEPS + 1) * BHID + (size_t)batch_d * HID + unit_d] = creg;
        }

        // ---- F: x_{t+2} cvt -> LDS parity p (safe: A(t) done block-wide) ----
        if (do_x) {
            const int b = tid >> 5, kx = (tid & 31) * 8;
            const float xv[8] = {xr0.x, xr0.y, xr0.z, xr0.w, xr1.x, xr1.y, xr1.z, xr1.w};
            bf16x8 a8, la8;
#pragma unroll
            for (int i = 0; i < 8; ++i) {
                const unsigned short h1 = f2bf(xv[i]);
                a8[i]  = (short)h1;
                la8[i] = (short)f2bf(xv[i] - __uint_as_float((unsigned)h1 << 16));
            }
            *reinterpret_cast<bf16x8*>(&xh_s[p][b][kx]) = a8;
            *reinterpret_cast<bf16x8*>(&xl_s[p][b][kx]) = la8;
        }
        // no end barrier: h dbuf (parity), x staged 2 ahead, skew bounded by MID
    }
}

extern "C" void kernel_launch(void* const* d_in, const int* in_sizes, int n_in,
                              void* d_out, int out_size, void* d_ws, size_t ws_size,
                              hipStream_t stream) {
    const float* seqs = (const float*)d_in[0];
    const float* h0   = (const float*)d_in[1];
    const float* c0   = (const float*)d_in[2];
    const float* Wi   = (const float*)d_in[3];
    const float* bi   = (const float*)d_in[4];
    const float* Wf   = (const float*)d_in[5];
    const float* bf   = (const float*)d_in[6];
    const float* Wg   = (const float*)d_in[7];
    const float* bg   = (const float*)d_in[8];
    const float* Wo   = (const float*)d_in[9];
    const float* bo   = (const float*)d_in[10];
    float* out = (float*)d_out;

    // Poison h[1..T] every launch: each element is written exactly once per
    // run, so the data itself is the readiness flag (graph-replay safe).
    hipMemsetAsync((char*)out + (size_t)BHID * 4, 0x7f,
                   (size_t)TSTEPS * BHID * 4, stream);

    hipLaunchKernelGGL(lstm_persistent, dim3(128), dim3(512), 0, stream,
                       seqs, h0, c0, Wi, bi, Wf, bf, Wg, bg, Wo, bo, out);
}

// Round 19
// 1250.447 us; speedup vs baseline: 6.5539x; 1.5992x over previous
//
#include <hip/hip_runtime.h>

// LSTM scan, persistent, per-element-poison sync + split-bf16 MFMA,
// all-gates-in-lane epilogue. T=512, B=64, D=256, H=512, K=768.
// R19 == R15 verbatim (session best: 1251us, passed). R16 (fewer producers):
// VGPR cliff, 6x regression. R17 (chunked poll pipeline): +67%. R18 (barrier
// removal + dbuf): +60% (poll storm). R15 is the measured local optimum; the
// residual ~1.2us/step of wait is the serialized cross-XCD LLC handoff chain
// (store flight -> LLC visibility -> detect -> stage), x512 steps.
// 8 groups x 16 blocks, 512 thr, NU=32. Group owns batches [8g,8g+8); block
// owns units [32r,32r+32); wave wv owns units u0+4wv..+3; A-row encoding
// row = u_local*4+gate => D fragment gives each lane all 4 gates of one
// (unit,batch): lane-local elementwise, c in a register.
// Sync: h elements self-flagging f32 dwords (poison 0x7f7f7f7f, each written
// once/run) through out; producers fire-and-forget sc0 sc1 dword stores;
// consumers speculatively bulk-load + per-thread retry.
// Lessons: LLC-only cross-CU visibility (R6/R7); only plain DWORD sc0 sc1
// stores proven visible (R11-13 NaNs); explicit vmcnt + sched_barrier after
// asm loads (R8); "=&v" early-clobber; bounded polls; <=512 thr (R16 cliff).

#define TSTEPS 512
#define BATCH 64
#define DIN 256
#define HID 512
#define KTOT 768
#define BHID (BATCH * HID)   // 32768
#define NB 8                 // batches per group
#define NU 32                // units per block
#define VROW 1064            // shorts/row: [h 512 | xhi 256 | xlo 256 | pad 40]
#define POISON 0x7f7f7f7fu

typedef __attribute__((ext_vector_type(8))) short bf16x8;
typedef __attribute__((ext_vector_type(4))) float f32x4;

__device__ __forceinline__ float4 llc_load4(const float* p) {
    float4 r; asm volatile("global_load_dwordx4 %0, %1, off sc0 sc1" : "=&v"(r) : "v"(p)); return r;
}
__device__ __forceinline__ void llc_store1(float* p, float v) {
    asm volatile("global_store_dword %0, %1, off sc0 sc1" :: "v"(p), "v"(v) : "memory");
}
__device__ __forceinline__ unsigned short f2bf(float f) {   // RNE float->bf16
    unsigned u = __float_as_uint(f);
    return (unsigned short)((u + 0x7fffu + ((u >> 16) & 1u)) >> 16);
}

__global__ __launch_bounds__(512, 1)
void lstm_persistent(const float* __restrict__ seqs,
                     const float* __restrict__ h0,
                     const float* __restrict__ c0,
                     const float* __restrict__ Wi, const float* __restrict__ bi,
                     const float* __restrict__ Wf, const float* __restrict__ bff,
                     const float* __restrict__ Wg, const float* __restrict__ bg,
                     const float* __restrict__ Wo, const float* __restrict__ bo,
                     float* __restrict__ out)   // [T+2][B][H]: h0, h1..hT, cT
{
    __shared__ __align__(16) short vv[NB * VROW];   // 17024 B

    const int tid  = threadIdx.x;
    const int bid  = blockIdx.x;
    const int g    = bid >> 4;         // group 0..7: batches [8g, 8g+8)
    const int rblk = bid & 15;         // 0..15: units [32r, 32r+32)
    const int b0 = g * NB;
    const int u0 = rblk * NU;

    const int wv  = tid >> 6;          // wave 0..7: owns units u0+4wv .. +3
    const int l   = tid & 63;
    const int n16 = l & 15;            // A row idx / D col (batch)
    const int khi = (l >> 4) & 3;      // k-subgroup / D row group (unit)
    const int bbr = l & 7;             // B-frag batch row (8-15 broadcast-dup)

    // ---- weights: lane n16 loads row (gate = n16&3, u_local = n16>>2) ----
    const int gsel = n16 & 3;
    const float* Wsel = (gsel == 0) ? Wi : (gsel == 1) ? Wf : (gsel == 2) ? Wg : Wo;
    const float* wrow = Wsel + (size_t)(u0 + 4 * wv + (n16 >> 2)) * KTOT;
    bf16x8 whi[24], wlo[24];
#pragma unroll
    for (int kt = 0; kt < 24; ++kt) {
        const int k0 = kt * 32 + khi * 8;
        const float4 a = *reinterpret_cast<const float4*>(wrow + k0);
        const float4 b = *reinterpret_cast<const float4*>(wrow + k0 + 4);
        const float vals[8] = {a.x, a.y, a.z, a.w, b.x, b.y, b.z, b.w};
        bf16x8 h8, l8;
#pragma unroll
        for (int i = 0; i < 8; ++i) {
            const unsigned short hv = f2bf(vals[i]);
            h8[i] = (short)hv;
            l8[i] = (short)f2bf(vals[i] - __uint_as_float((unsigned)hv << 16));
        }
        whi[kt] = h8; wlo[kt] = l8;
    }

    // ---- per-lane epilogue state: biases + c (unit_d, batch_d) ----
    const int unit_d  = u0 + 4 * wv + khi;
    const int batch_d = b0 + (n16 & 7);          // lanes 8-15 unused in E
    const float bI = bi[unit_d],  bF = bff[unit_d];
    const float bG = bg[unit_d],  bO = bo[unit_d];
    float creg = c0[(size_t)batch_d * HID + unit_d];

    if (tid < 256) {   // allhidden[0] = h0 slice (plain; never polled)
        const int uu = tid & 31, bb = tid >> 5;
        out[(size_t)(b0 + bb) * HID + u0 + uu] = h0[(size_t)(b0 + bb) * HID + u0 + uu];
    }

    // ---- pre-loop staging: h0 (bf16-hi) and x0 (hi+lo) -> LDS ----
    {
        const int b = tid >> 6, k0 = (tid & 63) * 8;
        const float* hp = h0 + (size_t)(b0 + b) * HID + k0;
        const float4 t0 = reinterpret_cast<const float4*>(hp)[0];
        const float4 t1 = reinterpret_cast<const float4*>(hp)[1];
        const float hv[8] = {t0.x, t0.y, t0.z, t0.w, t1.x, t1.y, t1.z, t1.w};
        bf16x8 a8;
#pragma unroll
        for (int i = 0; i < 8; ++i) a8[i] = (short)f2bf(hv[i]);
        *reinterpret_cast<bf16x8*>(&vv[b * VROW + k0]) = a8;
    }
    if (tid < 256) {
        const int b = tid >> 5, kx = (tid & 31) * 8;
        const float* xp = seqs + (size_t)(b0 + b) * DIN + kx;
        const float4 t0 = reinterpret_cast<const float4*>(xp)[0];
        const float4 t1 = reinterpret_cast<const float4*>(xp)[1];
        const float xv[8] = {t0.x, t0.y, t0.z, t0.w, t1.x, t1.y, t1.z, t1.w};
        bf16x8 a8, la8;
#pragma unroll
        for (int i = 0; i < 8; ++i) {
            const unsigned short h1 = f2bf(xv[i]);
            a8[i]  = (short)h1;
            la8[i] = (short)f2bf(xv[i] - __uint_as_float((unsigned)h1 << 16));
        }
        *reinterpret_cast<bf16x8*>(&vv[b * VROW + 512 + kx]) = a8;
        *reinterpret_cast<bf16x8*>(&vv[b * VROW + 768 + kx]) = la8;
    }
    __syncthreads();

    const short* vrow = &vv[bbr * VROW + khi * 8];

    for (int t = 0; t < TSTEPS; ++t) {
        // ---- C0: issue speculative h_t loads BEFORE the x-MFMA phase ----
        const int cb = tid >> 6, ck = (tid & 63) * 8;
        const float* hpf = out + (size_t)t * BHID + (size_t)(b0 + cb) * HID + ck;
        float4 hb0, hb1;
        if (t > 0) { hb0 = llc_load4(hpf); hb1 = llc_load4(hpf + 4); }

        // ---- A: x-part MFMA (uses x_t; overlaps other blocks' h_t tails) ----
        f32x4 aA = {0.f,0.f,0.f,0.f}, aB = {0.f,0.f,0.f,0.f}, aC = {0.f,0.f,0.f,0.f};
#pragma unroll
        for (int kt = 0; kt < 8; ++kt) {
            const bf16x8 bh = *reinterpret_cast<const bf16x8*>(vrow + 512 + kt * 32);
            const bf16x8 bl = *reinterpret_cast<const bf16x8*>(vrow + 768 + kt * 32);
            aA = __builtin_amdgcn_mfma_f32_16x16x32_bf16(whi[16 + kt], bh, aA, 0, 0, 0);
            aB = __builtin_amdgcn_mfma_f32_16x16x32_bf16(wlo[16 + kt], bh, aB, 0, 0, 0);
            aC = __builtin_amdgcn_mfma_f32_16x16x32_bf16(whi[16 + kt], bl, aC, 0, 0, 0);
        }

        // ---- B: issue x_{t+1} loads (complete under C/D) ----
        float4 xr0, xr1;
        const bool do_x = (t + 1 < TSTEPS) && (tid < 256);
        if (do_x) {
            const float* xp = seqs + (size_t)(t + 1) * BATCH * DIN
                            + (size_t)(b0 + (tid >> 5)) * DIN + (tid & 31) * 8;
            xr0 = reinterpret_cast<const float4*>(xp)[0];
            xr1 = reinterpret_cast<const float4*>(xp)[1];
        }

        // ---- C (t>0): speculative poll — data is its own flag ----
        if (t > 0) {
            unsigned miss = 0;
            for (;;) {
                asm volatile("s_waitcnt vmcnt(0)" ::: "memory");
                __builtin_amdgcn_sched_barrier(0);
                bool ok = true;
                ok &= (__float_as_uint(hb0.x) != POISON);
                ok &= (__float_as_uint(hb0.y) != POISON);
                ok &= (__float_as_uint(hb0.z) != POISON);
                ok &= (__float_as_uint(hb0.w) != POISON);
                ok &= (__float_as_uint(hb1.x) != POISON);
                ok &= (__float_as_uint(hb1.y) != POISON);
                ok &= (__float_as_uint(hb1.z) != POISON);
                ok &= (__float_as_uint(hb1.w) != POISON);
                if (ok) break;                    // per-thread readiness only
                if (++miss > (1u << 20)) break;   // bounded: never hang
                __builtin_amdgcn_s_sleep(1);
                hb0 = llc_load4(hpf); hb1 = llc_load4(hpf + 4);
            }
            const float hv[8] = {hb0.x, hb0.y, hb0.z, hb0.w, hb1.x, hb1.y, hb1.z, hb1.w};
            bf16x8 a8;
#pragma unroll
            for (int i = 0; i < 8; ++i) a8[i] = (short)f2bf(hv[i]);
            *reinterpret_cast<bf16x8*>(&vv[cb * VROW + ck]) = a8;
        }
        __syncthreads();   // h_t staged block-wide

        // ---- D: h-part MFMA (2 chains, h bf16-hi) ----
#pragma unroll
        for (int kt = 0; kt < 16; ++kt) {
            const bf16x8 bh = *reinterpret_cast<const bf16x8*>(vrow + kt * 32);
            aA = __builtin_amdgcn_mfma_f32_16x16x32_bf16(whi[kt], bh, aA, 0, 0, 0);
            aB = __builtin_amdgcn_mfma_f32_16x16x32_bf16(wlo[kt], bh, aB, 0, 0, 0);
        }
        const f32x4 gA = aA + aB + aC;   // gA[r] = gate r of (unit_d, batch_d)

        // ---- E: lane-local elementwise + fire-and-forget dword h store ----
        if (n16 < 8) {
            const float gi = gA[0] + bI;
            const float gf = gA[1] + bF;
            const float gG = gA[2] + bG;
            const float go = gA[3] + bO;
            const float i_ = 1.f / (1.f + __expf(-gi));
            const float f_ = 1.f / (1.f + __expf(-gf));
            const float o_ = 1.f / (1.f + __expf(-go));
            float eg = __expf(-2.f * fabsf(gG));
            float tg = (1.f - eg) / (1.f + eg);
            tg = (gG < 0.f) ? -tg : tg;
            creg = f_ * creg + i_ * tg;
            float ec = __expf(-2.f * fabsf(creg));
            float tc = (1.f - ec) / (1.f + ec);
            tc = (creg < 0.f) ? -tc : tc;
            const float hn = o_ * tc;
            llc_store1(out + (size_t)(t + 1) * BHID + (size_t)batch_d * HID + unit_d, hn);
            if (t == TSTEPS - 1)
                out[(size_t)(TSTEPS + 1) * BHID + (size_t)batch_d * HID + unit_d] = creg;
        }

        // ---- F: x_{t+1} cvt -> LDS ----
        if (do_x) {
            const int b = tid >> 5, kx = (tid & 31) * 8;
            const float xv[8] = {xr0.x, xr0.y, xr0.z, xr0.w, xr1.x, xr1.y, xr1.z, xr1.w};
            bf16x8 a8, la8;
#pragma unroll
            for (int i = 0; i < 8; ++i) {
                const unsigned short h1 = f2bf(xv[i]);
                a8[i]  = (short)h1;
                la8[i] = (short)f2bf(xv[i] - __uint_as_float((unsigned)h1 << 16));
            }
            *reinterpret_cast<bf16x8*>(&vv[b * VROW + 512 + kx]) = a8;
            *reinterpret_cast<bf16x8*>(&vv[b * VROW + 768 + kx]) = la8;
        }
        __syncthreads();   // x_{t+1} staged; h region free for next C
    }
}

extern "C" void kernel_launch(void* const* d_in, const int* in_sizes, int n_in,
                              void* d_out, int out_size, void* d_ws, size_t ws_size,
                              hipStream_t stream) {
    const float* seqs = (const float*)d_in[0];
    const float* h0   = (const float*)d_in[1];
    const float* c0   = (const float*)d_in[2];
    const float* Wi   = (const float*)d_in[3];
    const float* bi   = (const float*)d_in[4];
    const float* Wf   = (const float*)d_in[5];
    const float* bf   = (const float*)d_in[6];
    const float* Wg   = (const float*)d_in[7];
    const float* bg   = (const float*)d_in[8];
    const float* Wo   = (const float*)d_in[9];
    const float* bo   = (const float*)d_in[10];
    float* out = (float*)d_out;

    // Poison h[1..T] every launch: each element is written exactly once per
    // run, so the data itself is the readiness flag (graph-replay safe).
    hipMemsetAsync((char*)out + (size_t)BHID * 4, 0x7f,
                   (size_t)TSTEPS * BHID * 4, stream);

    hipLaunchKernelGGL(lstm_persistent, dim3(128), dim3(512), 0, stream,
                       seqs, h0, c0, Wi, bi, Wf, bf, Wg, bg, Wo, bo, out);
}